// Round 15
// baseline (339.963 us; speedup 1.0000x reference)
//
#include <hip/hip_runtime.h>
#include <hip/hip_bf16.h>
#include <math.h>

// Problem constants
#define TT 1024
#define DIM 1024
#define HH 8
#define QLR 768
#define KVLR 512
#define DNOPE 128
#define DROPE 64
#define DV 128
#define DK 192            // DNOPE + DROPE
#define HDK (HH*DK)       // 1536
#define HKV (HH*(DNOPE+DV)) // 2048

// Phase-A blob layout (floats) per (chunk n, head h):
#define OY   0
#define OQ   3072
#define OC   6144         // KcT [192][20] padded; slot 16 of each row = lam[d]
#define OPL  9984
#define OU   10240
#define OLAM 12288
#define PABLK 12480

typedef __attribute__((ext_vector_type(8))) short short8;
typedef __attribute__((ext_vector_type(4))) float f32x4;

// ---------------------------------------------------------------------------
// bf16 split helpers
// ---------------------------------------------------------------------------
__device__ __forceinline__ unsigned short f2bf_rn(float f) {
    unsigned u = __float_as_uint(f);
    unsigned lsb = (u >> 16) & 1u;
    u += 0x7fffu + lsb;
    return (unsigned short)(u >> 16);
}
__device__ __forceinline__ float bf2f(unsigned short h) {
    return __uint_as_float(((unsigned)h) << 16);
}

// ---------------------------------------------------------------------------
// Weight transpose+split: W[K][N] f32 -> Wt_h[N][K], Wt_l[N][K] bf16.
// ---------------------------------------------------------------------------
__global__ __launch_bounds__(256) void wconv(
    const float* __restrict__ W0, unsigned short* __restrict__ H0,
    unsigned short* __restrict__ L0, int K0, int N0, int T0,
    const float* __restrict__ W1, unsigned short* __restrict__ H1,
    unsigned short* __restrict__ L1, int K1, int N1, int T1,
    const float* __restrict__ W2, unsigned short* __restrict__ H2,
    unsigned short* __restrict__ L2, int K2, int N2, int T2)
{
    __shared__ float Ls[64][65];
    int bx = blockIdx.x;
    const float* W; unsigned short* H; unsigned short* L; int K, N;
    if (bx < T0)           { W = W0; H = H0; L = L0; K = K0; N = N0; }
    else if (bx < T0 + T1) { bx -= T0; W = W1; H = H1; L = L1; K = K1; N = N1; }
    else                   { bx -= T0 + T1; W = W2; H = H2; L = L2; K = K2; N = N2; }

    const int NT = N >> 6;
    const int kt = bx / NT, nt = bx - kt * NT;
    const int k0 = kt * 64, n0 = nt * 64;
    const int tid = threadIdx.x;
    const int r = tid >> 2, c = (tid & 3) * 16;

#pragma unroll
    for (int i = 0; i < 4; i++)
        *(float4*)&Ls[r][c + i * 4] =
            *(const float4*)&W[(size_t)(k0 + r) * N + n0 + c + i * 4];
    __syncthreads();

    const int nr = tid >> 2, kc = (tid & 3) * 16;
    unsigned short hb[16], lb[16];
#pragma unroll
    for (int j = 0; j < 16; j++) {
        float v = Ls[kc + j][nr];
        unsigned short h = f2bf_rn(v);
        hb[j] = h;
        lb[j] = f2bf_rn(v - bf2f(h));
    }
    size_t ob = (size_t)(n0 + nr) * K + k0 + kc;
    *(float4*)&H[ob]     = ((float4*)hb)[0];
    *(float4*)&H[ob + 8] = ((float4*)hb)[1];
    *(float4*)&L[ob]     = ((float4*)lb)[0];
    *(float4*)&L[ob + 8] = ((float4*)lb)[1];
}

// ---------------------------------------------------------------------------
// Activation split: A f32 -> H, L bf16.
// ---------------------------------------------------------------------------
__global__ __launch_bounds__(256) void aconv(
    const float* __restrict__ A, unsigned short* __restrict__ H,
    unsigned short* __restrict__ L)
{
    int i = (blockIdx.x * 256 + threadIdx.x) * 8;
    float4 v0 = *(const float4*)&A[i];
    float4 v1 = *(const float4*)&A[i + 4];
    float vv[8] = {v0.x, v0.y, v0.z, v0.w, v1.x, v1.y, v1.z, v1.w};
    unsigned short hb[8], lb[8];
#pragma unroll
    for (int j = 0; j < 8; j++) {
        unsigned short h = f2bf_rn(vv[j]);
        hb[j] = h;
        lb[j] = f2bf_rn(vv[j] - bf2f(h));
    }
    *(float4*)&H[i] = *(float4*)hb;
    *(float4*)&L[i] = *(float4*)lb;
}

// ---------------------------------------------------------------------------
// bf16x3 MFMA GEMM (unchanged from R10).
// ---------------------------------------------------------------------------
__global__ __launch_bounds__(128) void gemm_bt(
    const unsigned short* __restrict__ Ah0, const unsigned short* __restrict__ Al0,
    const unsigned short* __restrict__ Bh0, const unsigned short* __restrict__ Bl0,
    float* __restrict__ C0, int K0, int N0, int T0,
    const unsigned short* __restrict__ Ah1, const unsigned short* __restrict__ Al1,
    const unsigned short* __restrict__ Bh1, const unsigned short* __restrict__ Bl1,
    float* __restrict__ C1, int K1, int N1, int T1,
    const unsigned short* __restrict__ Ah2, const unsigned short* __restrict__ Al2,
    const unsigned short* __restrict__ Bh2, const unsigned short* __restrict__ Bl2,
    float* __restrict__ C2, int K2, int N2, int T2)
{
    __shared__ unsigned short Ahs[64 * 40], Als[64 * 40];
    __shared__ unsigned short Bhs[64 * 40], Bls[64 * 40];

    int bx = blockIdx.x;
    const unsigned short *Ah, *Al, *Bh, *Bl; float* C; int K, N;
    if (bx < T0) {
        Ah = Ah0; Al = Al0; Bh = Bh0; Bl = Bl0; C = C0; K = K0; N = N0;
    } else if (bx < T0 + T1) {
        bx -= T0; Ah = Ah1; Al = Al1; Bh = Bh1; Bl = Bl1; C = C1; K = K1; N = N1;
    } else {
        bx -= T0 + T1; Ah = Ah2; Al = Al2; Bh = Bh2; Bl = Bl2; C = C2; K = K2; N = N2;
    }

    const int tid = threadIdx.x;
    const int w = tid >> 6, l = tid & 63;
    const int q = l >> 4, m16 = l & 15;
    const int bm = blockIdx.y * 64, bn = bx * 64;

    const int c0i = tid * 2, c1i = tid * 2 + 1;
    const int r0 = c0i >> 2, o0 = (c0i & 3) * 8;
    const int r1 = c1i >> 2, o1 = (c1i & 3) * 8;
    const unsigned short* pAh0 = Ah + (size_t)(bm + r0) * K + o0;
    const unsigned short* pAh1 = Ah + (size_t)(bm + r1) * K + o1;
    const unsigned short* pAl0 = Al + (size_t)(bm + r0) * K + o0;
    const unsigned short* pAl1 = Al + (size_t)(bm + r1) * K + o1;
    const unsigned short* pBh0 = Bh + (size_t)(bn + r0) * K + o0;
    const unsigned short* pBh1 = Bh + (size_t)(bn + r1) * K + o1;
    const unsigned short* pBl0 = Bl + (size_t)(bn + r0) * K + o0;
    const unsigned short* pBl1 = Bl + (size_t)(bn + r1) * K + o1;

    f32x4 acc[2][4];
#pragma unroll
    for (int i = 0; i < 2; i++)
#pragma unroll
        for (int j = 0; j < 4; j++)
            acc[i][j] = (f32x4){0.f, 0.f, 0.f, 0.f};

    float4 vAh0 = *(const float4*)pAh0, vAh1 = *(const float4*)pAh1;
    float4 vAl0 = *(const float4*)pAl0, vAl1 = *(const float4*)pAl1;
    float4 vBh0 = *(const float4*)pBh0, vBh1 = *(const float4*)pBh1;
    float4 vBl0 = *(const float4*)pBl0, vBl1 = *(const float4*)pBl1;

    for (int k0 = 0;; k0 += 32) {
        __syncthreads();
        *(float4*)&Ahs[r0 * 40 + o0] = vAh0; *(float4*)&Ahs[r1 * 40 + o1] = vAh1;
        *(float4*)&Als[r0 * 40 + o0] = vAl0; *(float4*)&Als[r1 * 40 + o1] = vAl1;
        *(float4*)&Bhs[r0 * 40 + o0] = vBh0; *(float4*)&Bhs[r1 * 40 + o1] = vBh1;
        *(float4*)&Bls[r0 * 40 + o0] = vBl0; *(float4*)&Bls[r1 * 40 + o1] = vBl1;
        __syncthreads();

        const bool more = (k0 + 32) < K;
        if (more) {
            const int kn = k0 + 32;
            vAh0 = *(const float4*)(pAh0 + kn); vAh1 = *(const float4*)(pAh1 + kn);
            vAl0 = *(const float4*)(pAl0 + kn); vAl1 = *(const float4*)(pAl1 + kn);
            vBh0 = *(const float4*)(pBh0 + kn); vBh1 = *(const float4*)(pBh1 + kn);
            vBl0 = *(const float4*)(pBl0 + kn); vBl1 = *(const float4*)(pBl1 + kn);
        }

        short8 fah[2], fal[2], fbh[4], fbl[4];
#pragma unroll
        for (int mt = 0; mt < 2; mt++) {
            const int row = w * 32 + mt * 16 + m16;
            fah[mt] = *(const short8*)&Ahs[row * 40 + q * 8];
            fal[mt] = *(const short8*)&Als[row * 40 + q * 8];
        }
#pragma unroll
        for (int nt = 0; nt < 4; nt++) {
            const int row = nt * 16 + m16;
            fbh[nt] = *(const short8*)&Bhs[row * 40 + q * 8];
            fbl[nt] = *(const short8*)&Bls[row * 40 + q * 8];
        }
#pragma unroll
        for (int mt = 0; mt < 2; mt++)
#pragma unroll
            for (int nt = 0; nt < 4; nt++) {
                acc[mt][nt] = __builtin_amdgcn_mfma_f32_16x16x32_bf16(
                    fah[mt], fbh[nt], acc[mt][nt], 0, 0, 0);
                acc[mt][nt] = __builtin_amdgcn_mfma_f32_16x16x32_bf16(
                    fah[mt], fbl[nt], acc[mt][nt], 0, 0, 0);
                acc[mt][nt] = __builtin_amdgcn_mfma_f32_16x16x32_bf16(
                    fal[mt], fbh[nt], acc[mt][nt], 0, 0, 0);
            }
        if (!more) break;
    }

#pragma unroll
    for (int mt = 0; mt < 2; mt++)
#pragma unroll
        for (int nt = 0; nt < 4; nt++) {
            const int mrow = bm + w * 32 + mt * 16 + q * 4;
            const int ncol = bn + nt * 16 + m16;
#pragma unroll
            for (int r = 0; r < 4; r++)
                C[(size_t)(mrow + r) * N + ncol] = acc[mt][nt][r];
        }
}

// ---------------------------------------------------------------------------
// Fused RMSNorm (both norms in one launch; region-routed) -> bf16 hi/lo
// ---------------------------------------------------------------------------
__global__ __launch_bounds__(256) void rmsnorm_bf2(
    const float* __restrict__ in0, const float* __restrict__ w0,
    unsigned short* __restrict__ oh0, unsigned short* __restrict__ ol0,
    const float* __restrict__ in1, const float* __restrict__ w1,
    unsigned short* __restrict__ oh1, unsigned short* __restrict__ ol1)
{
    int bx = blockIdx.x;
    const float* in; const float* w; unsigned short *oh, *ol;
    int t, stride, ncols; float inv_n;
    if (bx < TT) {
        t = bx; in = in0; w = w0; oh = oh0; ol = ol0;
        stride = QLR; ncols = QLR; inv_n = 1.f / QLR;
    } else {
        t = bx - TT; in = in1; w = w1; oh = oh1; ol = ol1;
        stride = KVLR + DROPE; ncols = KVLR; inv_n = 1.f / KVLR;
    }
    const int tid = threadIdx.x;
    const float* row = in + (size_t)t * stride;
    float ss = 0.f;
    for (int c = tid; c < ncols; c += 256) { float v = row[c]; ss += v * v; }
#pragma unroll
    for (int m = 1; m < 64; m <<= 1) ss += __shfl_xor(ss, m);
    __shared__ float red[4];
    if ((tid & 63) == 0) red[tid >> 6] = ss;
    __syncthreads();
    float tot = red[0] + red[1] + red[2] + red[3];
    float scale = rsqrtf(tot * inv_n + 1e-5f);
    for (int c = tid; c < ncols; c += 256) {
        float v = row[c] * scale * w[c];
        unsigned short h = f2bf_rn(v);
        oh[(size_t)t * ncols + c] = h;
        ol[(size_t)t * ncols + c] = f2bf_rn(v - bf2f(h));
    }
}

// ---------------------------------------------------------------------------
// Fused small kernels: logsig_relayout [0,6144) + beta [6144,8192) +
// prep_qk [8192,10240). All block-range routed (wave-uniform).
// ---------------------------------------------------------------------------
__global__ __launch_bounds__(256) void small_fused(
    const float* __restrict__ g, const float* __restrict__ bias,
    float* __restrict__ la_h,
    const float* __restrict__ x, const float* __restrict__ wb,
    float* __restrict__ betab,
    const float* __restrict__ qraw, const float* __restrict__ kvb,
    const float* __restrict__ kv_all, float* __restrict__ q_h,
    float* __restrict__ k_h)
{
    int bx = blockIdx.x;
    if (bx < 6144) {
        int i = bx * 256 + threadIdx.x;   // < TT*HDK
        int t = i / HDK, col = i - t * HDK;
        int h = col / DK, d = col - h * DK;
        float z = g[i] + bias[col];
        float la = fminf(z, 0.f) - log1pf(__expf(-fabsf(z)));
        la_h[((size_t)h * TT + t) * DK + d] = la;
        return;
    }
    bx -= 6144;
    const int lane = threadIdx.x & 63, wv = threadIdx.x >> 6;
    if (bx < 2048) {
        const int p = bx * 4 + wv;        // p = t*8 + h
        const int t = p >> 3, h = p & 7;
        const float* xr = x + (size_t)t * DIM;
        float s = 0.f;
        for (int e = lane; e < DIM; e += 64) s += xr[e] * wb[e * HH + h];
#pragma unroll
        for (int m = 1; m < 64; m <<= 1) s += __shfl_xor(s, m);
        if (lane == 0) betab[p] = 1.f / (1.f + expf(-s));
        return;
    }
    bx -= 2048;
    {
        const int p = bx * 4 + wv;
        const int t = p >> 3, h = p & 7;

        const float* qrow = qraw + (size_t)t * HDK + h * DK;
        float q0 = qrow[lane], q1 = qrow[lane + 64], q2 = qrow[lane + 128];
        float ss = q0 * q0 + q1 * q1 + q2 * q2;
#pragma unroll
        for (int m = 1; m < 64; m <<= 1) ss += __shfl_xor(ss, m);
        float sc = rsqrtf(ss + 1e-6f) * 0.07216878364870323f;  // * DK^-0.5
        float* qo = q_h + ((size_t)h * TT + t) * DK;
        qo[lane] = q0 * sc; qo[lane + 64] = q1 * sc; qo[lane + 128] = q2 * sc;

        const float* knope = kvb + (size_t)t * HKV + h * (DNOPE + DV);
        float k0 = knope[lane], k1 = knope[lane + 64];
        float k2 = kv_all[(size_t)t * (KVLR + DROPE) + KVLR + lane];
        float ks = k0 * k0 + k1 * k1 + k2 * k2;
#pragma unroll
        for (int m = 1; m < 64; m <<= 1) ks += __shfl_xor(ks, m);
        float kc = rsqrtf(ks + 1e-6f);
        float* ko = k_h + ((size_t)h * TT + t) * DK;
        ko[lane] = k0 * kc; ko[lane + 64] = k1 * kc; ko[lane + 128] = k2 * kc;
    }
}

// ---------------------------------------------------------------------------
__device__ __forceinline__ float dpp_xor1(float x) {
    return __int_as_float(__builtin_amdgcn_update_dpp(
        0, __float_as_int(x), 0xB1, 0xF, 0xF, false));
}
__device__ __forceinline__ float dpp_xor2(float x) {
    return __int_as_float(__builtin_amdgcn_update_dpp(
        0, __float_as_int(x), 0x4E, 0xF, 0xF, false));
}
__device__ __forceinline__ float dpp_hm(float x) {   // row_half_mirror
    return __int_as_float(__builtin_amdgcn_update_dpp(
        0, __float_as_int(x), 0x141, 0xF, 0xF, false));
}
__device__ __forceinline__ float red16(float x) {
    x += dpp_xor1(x);
    x += dpp_xor2(x);
    x += dpp_hm(x);
    x += __int_as_float(__builtin_amdgcn_update_dpp(0, __float_as_int(x), 0x140, 0xF, 0xF, false));
    return x;
}
// 8-lane sum (lanes grouped by lane&7)
__device__ __forceinline__ float red8(float x) {
    x += dpp_xor1(x);
    x += dpp_xor2(x);
    x += dpp_hm(x);
    return x;
}

__device__ __forceinline__ void gl_lds16(const float* g, float* l) {
    __builtin_amdgcn_global_load_lds(
        (const __attribute__((address_space(1))) void*)g,
        (__attribute__((address_space(3))) void*)l, 16, 0, 0);
}
__device__ __forceinline__ void gl_lds4(const float* g, float* l) {
    __builtin_amdgcn_global_load_lds(
        (const __attribute__((address_space(1))) void*)g,
        (__attribute__((address_space(3))) void*)l, 4, 0, 0);
}

// ---------------------------------------------------------------------------
// Phase A: per-(chunk,head) S-independent quantities.
// Change vs R14: lam[d] is written into KcT row padding slot 16 so Phase B
// reads it with the same global dwordx4 as the row (saves LDS staging).
// ---------------------------------------------------------------------------
__global__ __launch_bounds__(256) void chunk_prep(
    const float* __restrict__ k_h, const float* __restrict__ la_h,
    const float* __restrict__ q_h, const float* __restrict__ kvb,
    const float* __restrict__ betab, float* __restrict__ pa)
{
    __shared__ float Ls[16][196];
    __shared__ float Ks[16][196];
    __shared__ float Qs[16][196];
    __shared__ float Ws[16][196];
    __shared__ float Xs[16][196];
    __shared__ float Ms[16][16];
    __shared__ float bs[16];

    const int tid = threadIdx.x;
    const int n = blockIdx.x >> 3, h = blockIdx.x & 7;
    const size_t g0 = ((size_t)h * TT + n * 16) * DK;
    float* blob = pa + (size_t)blockIdx.x * PABLK;

#pragma unroll
    for (int s = 0; s < 3; s++) {
        int off = (tid * 3 + s) * 4;
        int r = off / 192, c = off - r * 192;
        *(float4*)&Ks[r][c] = *(const float4*)(k_h + g0 + off);
        *(float4*)&Ls[r][c] = *(const float4*)(la_h + g0 + off);
        *(float4*)&Qs[r][c] = *(const float4*)(q_h + g0 + off);
    }
    if (tid < 16) bs[tid] = betab[(size_t)(n * 16 + tid) * HH + h];
    __syncthreads();

    if (tid < 192) {
        float g = 0.f;
#pragma unroll
        for (int i = 0; i < 16; i++) { g += Ls[i][tid]; Ls[i][tid] = g; }
    }
    __syncthreads();

#pragma unroll
    for (int s = 0; s < 12; s++) {
        int idx = s * 256 + tid;
        int i = idx / 192, d = idx - i * 192;
        float G = Ls[i][d];
        float eg = __expf(G), en = __expf(-G);
        float kk = Ks[i][d];
        Ws[i][d] = bs[i] * kk * eg;
        Qs[i][d] *= eg;
        Ks[i][d] = kk * en;
    }
    __syncthreads();

#pragma unroll
    for (int s = 0; s < 3; s++) {
        int off = (tid * 3 + s) * 4;
        int r = off / 192, c = off - r * 192;
        *(float4*)(blob + OQ + off) = *(const float4*)&Qs[r][c];
    }
    if (tid < 192) {
        float lam = __expf(Ls[15][tid]);
        blob[OLAM + tid] = lam;
#pragma unroll
        for (int j4 = 0; j4 < 4; j4++) {
            float4 v;
            v.x = Ks[j4 * 4 + 0][tid] * lam; v.y = Ks[j4 * 4 + 1][tid] * lam;
            v.z = Ks[j4 * 4 + 2][tid] * lam; v.w = Ks[j4 * 4 + 3][tid] * lam;
            *(float4*)(blob + OC + tid * 20 + j4 * 4) = v;
        }
        blob[OC + tid * 20 + 16] = lam;   // lam rides in the row padding
        blob[OC + tid * 20 + 17] = 0.f;
        blob[OC + tid * 20 + 18] = 0.f; blob[OC + tid * 20 + 19] = 0.f;
    }
    {
        const int i = tid >> 4, j = tid & 15;
        float m = 0.f, p = 0.f;
#pragma unroll
        for (int d4 = 0; d4 < 48; d4++) {
            float4 w  = *(const float4*)&Ws[i][d4 * 4];
            float4 ka = *(const float4*)&Ks[j][d4 * 4];
            float4 qa = *(const float4*)&Qs[i][d4 * 4];
            m += w.x * ka.x + w.y * ka.y + w.z * ka.z + w.w * ka.w;
            p += qa.x * ka.x + qa.y * ka.y + qa.z * ka.z + qa.w * ka.w;
        }
        Ms[i][j] = (j < i) ? m : 0.f;
        blob[OPL + tid] = (j <= i) ? p : 0.f;
    }
    __syncthreads();

    float y[16], uu[16];
    const bool doY = (tid < 192);
    const bool doU = (tid >= 128);
    const int dcol = tid, ccol = tid - 128;
    if (doY) {
#pragma unroll
        for (int i = 0; i < 16; i++) y[i] = Ws[i][dcol];
#pragma unroll
        for (int i = 1; i < 16; i++)
#pragma unroll
            for (int j = 0; j < i; j++)
                y[i] = fmaf(-Ms[i][j], y[j], y[i]);
    }
    if (doU) {
#pragma unroll
        for (int i = 0; i < 16; i++)
            uu[i] = bs[i] * kvb[(size_t)(n * 16 + i) * HKV + h * (DNOPE + DV) + DNOPE + ccol];
#pragma unroll
        for (int i = 1; i < 16; i++)
#pragma unroll
            for (int j = 0; j < i; j++)
                uu[i] = fmaf(-Ms[i][j], uu[j], uu[i]);
    }
    if (doY) {
#pragma unroll
        for (int i = 0; i < 16; i++) Xs[i][dcol] = y[i];
    }
    __syncthreads();
#pragma unroll
    for (int s = 0; s < 3; s++) {
        int off = (tid * 3 + s) * 4;
        int r = off / 192, c = off - r * 192;
        *(float4*)(blob + OY + off) = *(const float4*)&Xs[r][c];
    }
    __syncthreads();
    if (doU) {
#pragma unroll
        for (int i = 0; i < 16; i++) Xs[i][ccol] = uu[i];
    }
    __syncthreads();
#pragma unroll
    for (int s = 0; s < 2; s++) {
        int off = (tid * 2 + s) * 4;
        int r = off / 128, c = off - r * 128;
        *(float4*)(blob + OU + off) = *(const float4*)&Xs[r][c];
    }
}

// ---------------------------------------------------------------------------
// Phase B v7: Cb+lam read from GLOBAL into registers (per-thread-static rows,
// issued right after barrier A, consumed after barrier B -> a full z-phase of
// latency slack). LDS keeps only Pb/ubs (triple-buffered, tiny) + Ss + us
// (~5 KB). Y/Q also global (compiler schedules). Update on 192 thr x 2 dims.
// 512 blocks (8 h x 64 colgroups of 2 v-cols), 2+ blocks/CU.
// R14 audit: KcT LDS re-reads were 12 of ~20 b128/thread -> this removes them
// and the 15-instr Cb staging entirely.
// ---------------------------------------------------------------------------
__global__ __launch_bounds__(256) void kda_chunk(
    const float* __restrict__ pa, unsigned short* __restrict__ obh,
    unsigned short* __restrict__ obl)
{
    __shared__ float Pb[3][256];
    __shared__ float ubs[3][32];    // u' slice [16 ti][2 cc]
    __shared__ float Ss[392];       // state [2 cc][196]
    __shared__ float us[40];        // u [2 cc][20]

    const int tid = threadIdx.x;
    const int w = tid >> 6, lane = tid & 63;
    const int h = blockIdx.x >> 6, cg = blockIdx.x & 63;
    const int c0 = cg * 2;

    const int dg  = tid & 15;
    const int cc  = (tid >> 4) & 1;
    const int tig = tid >> 5;
    const int dbase = dg * 12;

    auto stage = [&](int buf, int n) {
        const float* blob = pa + (size_t)(n * 8 + h) * PABLK;
        if (w == 0) {
            gl_lds16(blob + OPL + lane * 4, &Pb[buf][0]);
            if (lane < 32)
                gl_lds4(blob + OU + (lane >> 1) * 128 + c0 + (lane & 1), &ubs[buf][0]);
        }
    };

    for (int idx = tid; idx < 392; idx += 256) Ss[idx] = 0.f;
    stage(0, 0);
    stage(1, 1);

    const int c2 = tid & 1, dseg = tid >> 1;   // update map (tid<192 active)
    const bool upd = (tid < 192);

    int buf = 0;
    for (int n = 0; n < TT / 16; n++) {
        __syncthreads();   // barrier A: Pb/ubs[buf] resident, Ss update visible

        if (n + 2 < TT / 16) {
            int b2 = buf + 2; if (b2 >= 3) b2 -= 3;
            stage(b2, n + 2);
        }

        const float* blob = pa + (size_t)(n * 8 + h) * PABLK;

        // early-issue Cb/lam global loads (consumed after barrier B)
        float4 cb0[4], cb1[4]; float lam0 = 0.f, lam1 = 0.f;
        if (upd) {
            const float* cp0 = blob + OC + (dseg * 2 + 0) * 20;
            const float* cp1 = blob + OC + (dseg * 2 + 1) * 20;
            cb0[0] = *(const float4*)(cp0);      cb0[1] = *(const float4*)(cp0 + 4);
            cb0[2] = *(const float4*)(cp0 + 8);  cb0[3] = *(const float4*)(cp0 + 12);
            lam0 = cp0[16];
            cb1[0] = *(const float4*)(cp1);      cb1[1] = *(const float4*)(cp1 + 4);
            cb1[2] = *(const float4*)(cp1 + 8);  cb1[3] = *(const float4*)(cp1 + 12);
            lam1 = cp1[16];
        }

        // Y/Q for this chunk (global, per-thread-static addresses)
        float4 Yc[2][3], Qc[2][3];
#pragma unroll
        for (int i = 0; i < 2; i++) {
            const float* py = blob + OY + (tig * 2 + i) * 192 + dbase;
            const float* pq = blob + OQ + (tig * 2 + i) * 192 + dbase;
#pragma unroll
            for (int s = 0; s < 3; s++) {
                Yc[i][s] = *(const float4*)(py + s * 4);
                Qc[i][s] = *(const float4*)(pq + s * 4);
            }
        }

        // z/zq: registers (Y/Q) x LDS (S): 2 ti x 1 cc per thread
        float4 sv[3];
#pragma unroll
        for (int s = 0; s < 3; s++)
            sv[s] = *(const float4*)&Ss[cc * 196 + dbase + s * 4];

        float py_[2] = {0.f, 0.f};
        float pq_[2] = {0.f, 0.f};
#pragma unroll
        for (int i = 0; i < 2; i++)
#pragma unroll
            for (int s = 0; s < 3; s++) {
                float4 yv = Yc[i][s];
                float4 qv = Qc[i][s];
                float4 s4 = sv[s];
                py_[i] = fmaf(yv.x, s4.x, py_[i]);
                py_[i] = fmaf(yv.y, s4.y, py_[i]);
                py_[i] = fmaf(yv.z, s4.z, py_[i]);
                py_[i] = fmaf(yv.w, s4.w, py_[i]);
                pq_[i] = fmaf(qv.x, s4.x, pq_[i]);
                pq_[i] = fmaf(qv.y, s4.y, pq_[i]);
                pq_[i] = fmaf(qv.z, s4.z, pq_[i]);
                pq_[i] = fmaf(qv.w, s4.w, pq_[i]);
            }
        float zy[2], zq[2];
#pragma unroll
        for (int i = 0; i < 2; i++) {
            zy[i] = red16(py_[i]);
            zq[i] = red16(pq_[i]);
        }

        float uv[2];
#pragma unroll
        for (int i = 0; i < 2; i++)
            uv[i] = ubs[buf][(tig * 2 + i) * 2 + cc] - zy[i];
        if ((dg & 7) == 0) {
            const int ii = dg >> 3;
            us[cc * 20 + tig * 2 + ii] = (ii == 0) ? uv[0] : uv[1];
        }
        __syncthreads();   // barrier B: us ready

        {
            const int ii = dg >> 3, qtr = dg & 7;
            const int ti = tig * 2 + ii;
            float acc = 0.f;
#pragma unroll
            for (int j = qtr; j <= 15; j += 8)
                if (j <= ti) acc = fmaf(Pb[buf][ti * 16 + j], us[cc * 20 + j], acc);
            acc = red8(acc);
            if (qtr == 0) {
                float ov = zq[ii] + acc;
                if (isnan(ov)) ov = 0.f;
                else if (isinf(ov)) ov = ov > 0.f ? 1e4f : -1e4f;
                size_t oi = (size_t)(n * 16 + ti) * (HH * DV) + h * DV + c0 + cc;
                unsigned short hb = f2bf_rn(ov);
                obh[oi] = hb;
                obl[oi] = f2bf_rn(ov - bf2f(hb));
            }
        }

        // state update from REGISTER Cb/lam: 192 threads x 2 dims x 1 col
        if (upd) {
            const float4* up = (const float4*)&us[c2 * 20];
            float4 u0 = up[0], u1 = up[1], u2v = up[2], u3 = up[3];
            const int d0 = dseg * 2, d1 = d0 + 1;
            {
                float a2 = lam0 * Ss[c2 * 196 + d0];
                a2 = fmaf(cb0[0].x, u0.x,  a2); a2 = fmaf(cb0[0].y, u0.y,  a2);
                a2 = fmaf(cb0[0].z, u0.z,  a2); a2 = fmaf(cb0[0].w, u0.w,  a2);
                a2 = fmaf(cb0[1].x, u1.x,  a2); a2 = fmaf(cb0[1].y, u1.y,  a2);
                a2 = fmaf(cb0[1].z, u1.z,  a2); a2 = fmaf(cb0[1].w, u1.w,  a2);
                a2 = fmaf(cb0[2].x, u2v.x, a2); a2 = fmaf(cb0[2].y, u2v.y, a2);
                a2 = fmaf(cb0[2].z, u2v.z, a2); a2 = fmaf(cb0[2].w, u2v.w, a2);
                a2 = fmaf(cb0[3].x, u3.x,  a2); a2 = fmaf(cb0[3].y, u3.y,  a2);
                a2 = fmaf(cb0[3].z, u3.z,  a2); a2 = fmaf(cb0[3].w, u3.w,  a2);
                Ss[c2 * 196 + d0] = a2;
            }
            {
                float a2 = lam1 * Ss[c2 * 196 + d1];
                a2 = fmaf(cb1[0].x, u0.x,  a2); a2 = fmaf(cb1[0].y, u0.y,  a2);
                a2 = fmaf(cb1[0].z, u0.z,  a2); a2 = fmaf(cb1[0].w, u0.w,  a2);
                a2 = fmaf(cb1[1].x, u1.x,  a2); a2 = fmaf(cb1[1].y, u1.y,  a2);
                a2 = fmaf(cb1[1].z, u1.z,  a2); a2 = fmaf(cb1[1].w, u1.w,  a2);
                a2 = fmaf(cb1[2].x, u2v.x, a2); a2 = fmaf(cb1[2].y, u2v.y, a2);
                a2 = fmaf(cb1[2].z, u2v.z, a2); a2 = fmaf(cb1[2].w, u2v.w, a2);
                a2 = fmaf(cb1[3].x, u3.x,  a2); a2 = fmaf(cb1[3].y, u3.y,  a2);
                a2 = fmaf(cb1[3].z, u3.z,  a2); a2 = fmaf(cb1[3].w, u3.w,  a2);
                Ss[c2 * 196 + d1] = a2;
            }
        }
        // no barrier C: next iteration's barrier A orders Ss/us reuse
        buf = (buf + 1 == 3) ? 0 : buf + 1;
    }
}

// ---------------------------------------------------------------------------
extern "C" void kernel_launch(void* const* d_in, const int* in_sizes, int n_in,
                              void* d_out, int out_size, void* d_ws, size_t ws_size,
                              hipStream_t stream)
{
    const float* x         = (const float*)d_in[0];
    // d_in[1] = cos, d_in[2] = sin : unused by the reference
    const float* wq_a      = (const float*)d_in[3];
    const float* q_norm_w  = (const float*)d_in[4];
    const float* wq_b      = (const float*)d_in[5];
    const float* wkv_a     = (const float*)d_in[6];
    const float* kv_norm_w = (const float*)d_in[7];
    const float* wkv_b     = (const float*)d_in[8];
    const float* wg_w      = (const float*)d_in[9];
    const float* wg_b      = (const float*)d_in[10];
    const float* wb        = (const float*)d_in[11];
    const float* wo        = (const float*)d_in[12];
    float* out = (float*)d_out;

    float* ws = (float*)d_ws;
    float* xq     = ws;                        // T x 768 (f32, gemm1 out)
    float* kv_all = xq     + TT * QLR;         // T x 576
    float* agraw  = kv_all + TT * (KVLR + DROPE); // T x 1536 (dead after logsig)
    float* qnraw  = agraw  + TT * HDK;         // T x 1536
    float* kvb    = qnraw  + TT * HDK;         // T x 2048
    float* la_h   = kvb    + TT * HKV;         // 8 x 1024 x 192
    float* q_h    = la_h   + TT * HDK;
    float* k_h    = q_h    + TT * HDK;
    float* betab  = k_h    + TT * HDK;         // T x 8
    float* pa     = betab  + TT * HH;          // 512 x PABLK (25.6 MB)
    float* tail   = pa     + 512 * PABLK;

    unsigned short* wo_h  = (unsigned short*)tail;          // 1024*1024
    unsigned short* wo_l  = wo_h  + 1048576;
    unsigned short* xh    = wo_l  + 1048576;                // 1024*1024
    unsigned short* xl    = xh    + 1048576;
    unsigned short* xqh   = xl    + 1048576;                // 1024*768
    unsigned short* xql   = xqh   + 786432;
    unsigned short* kvnh  = xql   + 786432;                 // 1024*512
    unsigned short* kvnl  = kvnh  + 524288;

    unsigned short* wqa_h  = (unsigned short*)pa;           // 768n x 1024k
    unsigned short* wqa_l  = wqa_h  + 786432;
    unsigned short* wkva_h = wqa_l  + 786432;               // 576n x 1024k
    unsigned short* wkva_l = wkva_h + 589824;
    unsigned short* wgw_h  = wkva_l + 589824;               // 1536n x 1024k
    unsigned short* wgw_l  = wgw_h  + 1572864;
    unsigned short* wqb_h  = wgw_l  + 1572864;              // 1536n x 768k
    unsigned short* wqb_l  = wqb_h  + 1179648;
    unsigned short* wkvb_h = wqb_l  + 1179648;              // 2048n x 512k
    unsigned short* wkvb_l = wkvb_h + 1048576;

    unsigned short* obh = (unsigned short*)agraw;           // 1024*1024
    unsigned short* obl = obh + 1048576;

    dim3 blk(256);

    wconv<<<dim3(192 + 144 + 384), blk, 0, stream>>>(
        wq_a, wqa_h, wqa_l, DIM, QLR, 192,
        wkv_a, wkva_h, wkva_l, DIM, KVLR + DROPE, 144,
        wg_w, wgw_h, wgw_l, DIM, HDK, 384);
    wconv<<<dim3(288 + 256 + 256), blk, 0, stream>>>(
        wq_b, wqb_h, wqb_l, QLR, HDK, 288,
        wkv_b, wkvb_h, wkvb_l, KVLR, HKV, 256,
        wo, wo_h, wo_l, DIM, DIM, 256);

    aconv<<<dim3(TT * DIM / (256 * 8)), blk, 0, stream>>>(x, xh, xl);

    gemm_bt<<<dim3(12 + 9 + 24, 16), dim3(128), 0, stream>>>(
        xh, xl, wqa_h, wqa_l, xq, DIM, QLR, 12,
        xh, xl, wkva_h, wkva_l, kv_all, DIM, KVLR + DROPE, 9,
        xh, xl, wgw_h, wgw_l, agraw, DIM, HDK, 24);

    rmsnorm_bf2<<<dim3(2 * TT), blk, 0, stream>>>(
        xq, q_norm_w, xqh, xql,
        kv_all, kv_norm_w, kvnh, kvnl);

    gemm_bt<<<dim3(24 + 32, 16), dim3(128), 0, stream>>>(
        xqh, xql, wqb_h, wqb_l, qnraw, QLR, HDK, 24,
        kvnh, kvnl, wkvb_h, wkvb_l, kvb, KVLR, HKV, 32,
        xh, xl, wqa_h, wqa_l, xq, DIM, QLR, 0);

    small_fused<<<dim3(6144 + 2048 + 2048), blk, 0, stream>>>(
        agraw, wg_b, la_h,
        x, wb, betab,
        qnraw, kvb, kv_all, q_h, k_h);

    chunk_prep<<<512, blk, 0, stream>>>(k_h, la_h, q_h, kvb, betab, pa);
    kda_chunk<<<512, blk, 0, stream>>>(pa, obh, obl);

    gemm_bt<<<dim3(16, 16), dim3(128), 0, stream>>>(
        obh, obl, wo_h, wo_l, out, DIM, DIM, 16,
        xh, xl, wqa_h, wqa_l, xq, DIM, QLR, 0,
        xh, xl, wqa_h, wqa_l, xq, DIM, QLR, 0);
}

// Round 16
// 315.577 us; speedup vs baseline: 1.0773x; 1.0773x over previous
//
#include <hip/hip_runtime.h>
#include <hip/hip_bf16.h>
#include <math.h>

// Problem constants
#define TT 1024
#define DIM 1024
#define HH 8
#define QLR 768
#define KVLR 512
#define DNOPE 128
#define DROPE 64
#define DV 128
#define DK 192            // DNOPE + DROPE
#define HDK (HH*DK)       // 1536
#define HKV (HH*(DNOPE+DV)) // 2048

// Phase-A blob layout (floats) per (chunk n, head h):
#define OY   0
#define OQ   3072
#define OC   6144         // KcT [192][20] padded; slot 16 of each row = lam[d]
#define OPL  9984
#define OU   10240
#define OLAM 12288
#define PABLK 12480

typedef __attribute__((ext_vector_type(8))) short short8;
typedef __attribute__((ext_vector_type(4))) float f32x4;

// ---------------------------------------------------------------------------
// bf16 split helpers
// ---------------------------------------------------------------------------
__device__ __forceinline__ unsigned short f2bf_rn(float f) {
    unsigned u = __float_as_uint(f);
    unsigned lsb = (u >> 16) & 1u;
    u += 0x7fffu + lsb;
    return (unsigned short)(u >> 16);
}
__device__ __forceinline__ float bf2f(unsigned short h) {
    return __uint_as_float(((unsigned)h) << 16);
}

// ---------------------------------------------------------------------------
// Weight transpose+split: W[K][N] f32 -> Wt_h[N][K], Wt_l[N][K] bf16.
// ---------------------------------------------------------------------------
__global__ __launch_bounds__(256) void wconv(
    const float* __restrict__ W0, unsigned short* __restrict__ H0,
    unsigned short* __restrict__ L0, int K0, int N0, int T0,
    const float* __restrict__ W1, unsigned short* __restrict__ H1,
    unsigned short* __restrict__ L1, int K1, int N1, int T1,
    const float* __restrict__ W2, unsigned short* __restrict__ H2,
    unsigned short* __restrict__ L2, int K2, int N2, int T2)
{
    __shared__ float Ls[64][65];
    int bx = blockIdx.x;
    const float* W; unsigned short* H; unsigned short* L; int K, N;
    if (bx < T0)           { W = W0; H = H0; L = L0; K = K0; N = N0; }
    else if (bx < T0 + T1) { bx -= T0; W = W1; H = H1; L = L1; K = K1; N = N1; }
    else                   { bx -= T0 + T1; W = W2; H = H2; L = L2; K = K2; N = N2; }

    const int NT = N >> 6;
    const int kt = bx / NT, nt = bx - kt * NT;
    const int k0 = kt * 64, n0 = nt * 64;
    const int tid = threadIdx.x;
    const int r = tid >> 2, c = (tid & 3) * 16;

#pragma unroll
    for (int i = 0; i < 4; i++)
        *(float4*)&Ls[r][c + i * 4] =
            *(const float4*)&W[(size_t)(k0 + r) * N + n0 + c + i * 4];
    __syncthreads();

    const int nr = tid >> 2, kc = (tid & 3) * 16;
    unsigned short hb[16], lb[16];
#pragma unroll
    for (int j = 0; j < 16; j++) {
        float v = Ls[kc + j][nr];
        unsigned short h = f2bf_rn(v);
        hb[j] = h;
        lb[j] = f2bf_rn(v - bf2f(h));
    }
    size_t ob = (size_t)(n0 + nr) * K + k0 + kc;
    *(float4*)&H[ob]     = ((float4*)hb)[0];
    *(float4*)&H[ob + 8] = ((float4*)hb)[1];
    *(float4*)&L[ob]     = ((float4*)lb)[0];
    *(float4*)&L[ob + 8] = ((float4*)lb)[1];
}

// ---------------------------------------------------------------------------
// Activation split: A f32 -> H, L bf16.
// ---------------------------------------------------------------------------
__global__ __launch_bounds__(256) void aconv(
    const float* __restrict__ A, unsigned short* __restrict__ H,
    unsigned short* __restrict__ L)
{
    int i = (blockIdx.x * 256 + threadIdx.x) * 8;
    float4 v0 = *(const float4*)&A[i];
    float4 v1 = *(const float4*)&A[i + 4];
    float vv[8] = {v0.x, v0.y, v0.z, v0.w, v1.x, v1.y, v1.z, v1.w};
    unsigned short hb[8], lb[8];
#pragma unroll
    for (int j = 0; j < 8; j++) {
        unsigned short h = f2bf_rn(vv[j]);
        hb[j] = h;
        lb[j] = f2bf_rn(vv[j] - bf2f(h));
    }
    *(float4*)&H[i] = *(float4*)hb;
    *(float4*)&L[i] = *(float4*)lb;
}

// ---------------------------------------------------------------------------
// bf16x3 MFMA GEMM (unchanged from R10).
// ---------------------------------------------------------------------------
__global__ __launch_bounds__(128) void gemm_bt(
    const unsigned short* __restrict__ Ah0, const unsigned short* __restrict__ Al0,
    const unsigned short* __restrict__ Bh0, const unsigned short* __restrict__ Bl0,
    float* __restrict__ C0, int K0, int N0, int T0,
    const unsigned short* __restrict__ Ah1, const unsigned short* __restrict__ Al1,
    const unsigned short* __restrict__ Bh1, const unsigned short* __restrict__ Bl1,
    float* __restrict__ C1, int K1, int N1, int T1,
    const unsigned short* __restrict__ Ah2, const unsigned short* __restrict__ Al2,
    const unsigned short* __restrict__ Bh2, const unsigned short* __restrict__ Bl2,
    float* __restrict__ C2, int K2, int N2, int T2)
{
    __shared__ unsigned short Ahs[64 * 40], Als[64 * 40];
    __shared__ unsigned short Bhs[64 * 40], Bls[64 * 40];

    int bx = blockIdx.x;
    const unsigned short *Ah, *Al, *Bh, *Bl; float* C; int K, N;
    if (bx < T0) {
        Ah = Ah0; Al = Al0; Bh = Bh0; Bl = Bl0; C = C0; K = K0; N = N0;
    } else if (bx < T0 + T1) {
        bx -= T0; Ah = Ah1; Al = Al1; Bh = Bh1; Bl = Bl1; C = C1; K = K1; N = N1;
    } else {
        bx -= T0 + T1; Ah = Ah2; Al = Al2; Bh = Bh2; Bl = Bl2; C = C2; K = K2; N = N2;
    }

    const int tid = threadIdx.x;
    const int w = tid >> 6, l = tid & 63;
    const int q = l >> 4, m16 = l & 15;
    const int bm = blockIdx.y * 64, bn = bx * 64;

    const int c0i = tid * 2, c1i = tid * 2 + 1;
    const int r0 = c0i >> 2, o0 = (c0i & 3) * 8;
    const int r1 = c1i >> 2, o1 = (c1i & 3) * 8;
    const unsigned short* pAh0 = Ah + (size_t)(bm + r0) * K + o0;
    const unsigned short* pAh1 = Ah + (size_t)(bm + r1) * K + o1;
    const unsigned short* pAl0 = Al + (size_t)(bm + r0) * K + o0;
    const unsigned short* pAl1 = Al + (size_t)(bm + r1) * K + o1;
    const unsigned short* pBh0 = Bh + (size_t)(bn + r0) * K + o0;
    const unsigned short* pBh1 = Bh + (size_t)(bn + r1) * K + o1;
    const unsigned short* pBl0 = Bl + (size_t)(bn + r0) * K + o0;
    const unsigned short* pBl1 = Bl + (size_t)(bn + r1) * K + o1;

    f32x4 acc[2][4];
#pragma unroll
    for (int i = 0; i < 2; i++)
#pragma unroll
        for (int j = 0; j < 4; j++)
            acc[i][j] = (f32x4){0.f, 0.f, 0.f, 0.f};

    float4 vAh0 = *(const float4*)pAh0, vAh1 = *(const float4*)pAh1;
    float4 vAl0 = *(const float4*)pAl0, vAl1 = *(const float4*)pAl1;
    float4 vBh0 = *(const float4*)pBh0, vBh1 = *(const float4*)pBh1;
    float4 vBl0 = *(const float4*)pBl0, vBl1 = *(const float4*)pBl1;

    for (int k0 = 0;; k0 += 32) {
        __syncthreads();
        *(float4*)&Ahs[r0 * 40 + o0] = vAh0; *(float4*)&Ahs[r1 * 40 + o1] = vAh1;
        *(float4*)&Als[r0 * 40 + o0] = vAl0; *(float4*)&Als[r1 * 40 + o1] = vAl1;
        *(float4*)&Bhs[r0 * 40 + o0] = vBh0; *(float4*)&Bhs[r1 * 40 + o1] = vBh1;
        *(float4*)&Bls[r0 * 40 + o0] = vBl0; *(float4*)&Bls[r1 * 40 + o1] = vBl1;
        __syncthreads();

        const bool more = (k0 + 32) < K;
        if (more) {
            const int kn = k0 + 32;
            vAh0 = *(const float4*)(pAh0 + kn); vAh1 = *(const float4*)(pAh1 + kn);
            vAl0 = *(const float4*)(pAl0 + kn); vAl1 = *(const float4*)(pAl1 + kn);
            vBh0 = *(const float4*)(pBh0 + kn); vBh1 = *(const float4*)(pBh1 + kn);
            vBl0 = *(const float4*)(pBl0 + kn); vBl1 = *(const float4*)(pBl1 + kn);
        }

        short8 fah[2], fal[2], fbh[4], fbl[4];
#pragma unroll
        for (int mt = 0; mt < 2; mt++) {
            const int row = w * 32 + mt * 16 + m16;
            fah[mt] = *(const short8*)&Ahs[row * 40 + q * 8];
            fal[mt] = *(const short8*)&Als[row * 40 + q * 8];
        }
#pragma unroll
        for (int nt = 0; nt < 4; nt++) {
            const int row = nt * 16 + m16;
            fbh[nt] = *(const short8*)&Bhs[row * 40 + q * 8];
            fbl[nt] = *(const short8*)&Bls[row * 40 + q * 8];
        }
#pragma unroll
        for (int mt = 0; mt < 2; mt++)
#pragma unroll
            for (int nt = 0; nt < 4; nt++) {
                acc[mt][nt] = __builtin_amdgcn_mfma_f32_16x16x32_bf16(
                    fah[mt], fbh[nt], acc[mt][nt], 0, 0, 0);
                acc[mt][nt] = __builtin_amdgcn_mfma_f32_16x16x32_bf16(
                    fah[mt], fbl[nt], acc[mt][nt], 0, 0, 0);
                acc[mt][nt] = __builtin_amdgcn_mfma_f32_16x16x32_bf16(
                    fal[mt], fbh[nt], acc[mt][nt], 0, 0, 0);
            }
        if (!more) break;
    }

#pragma unroll
    for (int mt = 0; mt < 2; mt++)
#pragma unroll
        for (int nt = 0; nt < 4; nt++) {
            const int mrow = bm + w * 32 + mt * 16 + q * 4;
            const int ncol = bn + nt * 16 + m16;
#pragma unroll
            for (int r = 0; r < 4; r++)
                C[(size_t)(mrow + r) * N + ncol] = acc[mt][nt][r];
        }
}

// ---------------------------------------------------------------------------
// Fused RMSNorm (both norms in one launch; region-routed) -> bf16 hi/lo
// ---------------------------------------------------------------------------
__global__ __launch_bounds__(256) void rmsnorm_bf2(
    const float* __restrict__ in0, const float* __restrict__ w0,
    unsigned short* __restrict__ oh0, unsigned short* __restrict__ ol0,
    const float* __restrict__ in1, const float* __restrict__ w1,
    unsigned short* __restrict__ oh1, unsigned short* __restrict__ ol1)
{
    int bx = blockIdx.x;
    const float* in; const float* w; unsigned short *oh, *ol;
    int t, stride, ncols; float inv_n;
    if (bx < TT) {
        t = bx; in = in0; w = w0; oh = oh0; ol = ol0;
        stride = QLR; ncols = QLR; inv_n = 1.f / QLR;
    } else {
        t = bx - TT; in = in1; w = w1; oh = oh1; ol = ol1;
        stride = KVLR + DROPE; ncols = KVLR; inv_n = 1.f / KVLR;
    }
    const int tid = threadIdx.x;
    const float* row = in + (size_t)t * stride;
    float ss = 0.f;
    for (int c = tid; c < ncols; c += 256) { float v = row[c]; ss += v * v; }
#pragma unroll
    for (int m = 1; m < 64; m <<= 1) ss += __shfl_xor(ss, m);
    __shared__ float red[4];
    if ((tid & 63) == 0) red[tid >> 6] = ss;
    __syncthreads();
    float tot = red[0] + red[1] + red[2] + red[3];
    float scale = rsqrtf(tot * inv_n + 1e-5f);
    for (int c = tid; c < ncols; c += 256) {
        float v = row[c] * scale * w[c];
        unsigned short h = f2bf_rn(v);
        oh[(size_t)t * ncols + c] = h;
        ol[(size_t)t * ncols + c] = f2bf_rn(v - bf2f(h));
    }
}

// ---------------------------------------------------------------------------
// Fused small kernels: logsig_relayout [0,6144) + beta [6144,8192) +
// prep_qk [8192,10240). All block-range routed (wave-uniform).
// ---------------------------------------------------------------------------
__global__ __launch_bounds__(256) void small_fused(
    const float* __restrict__ g, const float* __restrict__ bias,
    float* __restrict__ la_h,
    const float* __restrict__ x, const float* __restrict__ wb,
    float* __restrict__ betab,
    const float* __restrict__ qraw, const float* __restrict__ kvb,
    const float* __restrict__ kv_all, float* __restrict__ q_h,
    float* __restrict__ k_h)
{
    int bx = blockIdx.x;
    if (bx < 6144) {
        int i = bx * 256 + threadIdx.x;   // < TT*HDK
        int t = i / HDK, col = i - t * HDK;
        int h = col / DK, d = col - h * DK;
        float z = g[i] + bias[col];
        float la = fminf(z, 0.f) - log1pf(__expf(-fabsf(z)));
        la_h[((size_t)h * TT + t) * DK + d] = la;
        return;
    }
    bx -= 6144;
    const int lane = threadIdx.x & 63, wv = threadIdx.x >> 6;
    if (bx < 2048) {
        const int p = bx * 4 + wv;        // p = t*8 + h
        const int t = p >> 3, h = p & 7;
        const float* xr = x + (size_t)t * DIM;
        float s = 0.f;
        for (int e = lane; e < DIM; e += 64) s += xr[e] * wb[e * HH + h];
#pragma unroll
        for (int m = 1; m < 64; m <<= 1) s += __shfl_xor(s, m);
        if (lane == 0) betab[p] = 1.f / (1.f + expf(-s));
        return;
    }
    bx -= 2048;
    {
        const int p = bx * 4 + wv;
        const int t = p >> 3, h = p & 7;

        const float* qrow = qraw + (size_t)t * HDK + h * DK;
        float q0 = qrow[lane], q1 = qrow[lane + 64], q2 = qrow[lane + 128];
        float ss = q0 * q0 + q1 * q1 + q2 * q2;
#pragma unroll
        for (int m = 1; m < 64; m <<= 1) ss += __shfl_xor(ss, m);
        float sc = rsqrtf(ss + 1e-6f) * 0.07216878364870323f;  // * DK^-0.5
        float* qo = q_h + ((size_t)h * TT + t) * DK;
        qo[lane] = q0 * sc; qo[lane + 64] = q1 * sc; qo[lane + 128] = q2 * sc;

        const float* knope = kvb + (size_t)t * HKV + h * (DNOPE + DV);
        float k0 = knope[lane], k1 = knope[lane + 64];
        float k2 = kv_all[(size_t)t * (KVLR + DROPE) + KVLR + lane];
        float ks = k0 * k0 + k1 * k1 + k2 * k2;
#pragma unroll
        for (int m = 1; m < 64; m <<= 1) ks += __shfl_xor(ks, m);
        float kc = rsqrtf(ks + 1e-6f);
        float* ko = k_h + ((size_t)h * TT + t) * DK;
        ko[lane] = k0 * kc; ko[lane + 64] = k1 * kc; ko[lane + 128] = k2 * kc;
    }
}

// ---------------------------------------------------------------------------
__device__ __forceinline__ float dpp_xor1(float x) {
    return __int_as_float(__builtin_amdgcn_update_dpp(
        0, __float_as_int(x), 0xB1, 0xF, 0xF, false));
}
__device__ __forceinline__ float dpp_xor2(float x) {
    return __int_as_float(__builtin_amdgcn_update_dpp(
        0, __float_as_int(x), 0x4E, 0xF, 0xF, false));
}
__device__ __forceinline__ float dpp_hm(float x) {   // row_half_mirror
    return __int_as_float(__builtin_amdgcn_update_dpp(
        0, __float_as_int(x), 0x141, 0xF, 0xF, false));
}
__device__ __forceinline__ float red16(float x) {
    x += dpp_xor1(x);
    x += dpp_xor2(x);
    x += dpp_hm(x);
    x += __int_as_float(__builtin_amdgcn_update_dpp(0, __float_as_int(x), 0x140, 0xF, 0xF, false));
    return x;
}
// 8-lane sum (lanes grouped by lane&7)
__device__ __forceinline__ float red8(float x) {
    x += dpp_xor1(x);
    x += dpp_xor2(x);
    x += dpp_hm(x);
    return x;
}

__device__ __forceinline__ void gl_lds16(const float* g, float* l) {
    __builtin_amdgcn_global_load_lds(
        (const __attribute__((address_space(1))) void*)g,
        (__attribute__((address_space(3))) void*)l, 16, 0, 0);
}
__device__ __forceinline__ void gl_lds4(const float* g, float* l) {
    __builtin_amdgcn_global_load_lds(
        (const __attribute__((address_space(1))) void*)g,
        (__attribute__((address_space(3))) void*)l, 4, 0, 0);
}

// ---------------------------------------------------------------------------
// Phase A: per-(chunk,head) S-independent quantities (unchanged from R15;
// lam in row padding is harmless alongside OLAM).
// ---------------------------------------------------------------------------
__global__ __launch_bounds__(256) void chunk_prep(
    const float* __restrict__ k_h, const float* __restrict__ la_h,
    const float* __restrict__ q_h, const float* __restrict__ kvb,
    const float* __restrict__ betab, float* __restrict__ pa)
{
    __shared__ float Ls[16][196];
    __shared__ float Ks[16][196];
    __shared__ float Qs[16][196];
    __shared__ float Ws[16][196];
    __shared__ float Xs[16][196];
    __shared__ float Ms[16][16];
    __shared__ float bs[16];

    const int tid = threadIdx.x;
    const int n = blockIdx.x >> 3, h = blockIdx.x & 7;
    const size_t g0 = ((size_t)h * TT + n * 16) * DK;
    float* blob = pa + (size_t)blockIdx.x * PABLK;

#pragma unroll
    for (int s = 0; s < 3; s++) {
        int off = (tid * 3 + s) * 4;
        int r = off / 192, c = off - r * 192;
        *(float4*)&Ks[r][c] = *(const float4*)(k_h + g0 + off);
        *(float4*)&Ls[r][c] = *(const float4*)(la_h + g0 + off);
        *(float4*)&Qs[r][c] = *(const float4*)(q_h + g0 + off);
    }
    if (tid < 16) bs[tid] = betab[(size_t)(n * 16 + tid) * HH + h];
    __syncthreads();

    if (tid < 192) {
        float g = 0.f;
#pragma unroll
        for (int i = 0; i < 16; i++) { g += Ls[i][tid]; Ls[i][tid] = g; }
    }
    __syncthreads();

#pragma unroll
    for (int s = 0; s < 12; s++) {
        int idx = s * 256 + tid;
        int i = idx / 192, d = idx - i * 192;
        float G = Ls[i][d];
        float eg = __expf(G), en = __expf(-G);
        float kk = Ks[i][d];
        Ws[i][d] = bs[i] * kk * eg;
        Qs[i][d] *= eg;
        Ks[i][d] = kk * en;
    }
    __syncthreads();

#pragma unroll
    for (int s = 0; s < 3; s++) {
        int off = (tid * 3 + s) * 4;
        int r = off / 192, c = off - r * 192;
        *(float4*)(blob + OQ + off) = *(const float4*)&Qs[r][c];
    }
    if (tid < 192) {
        float lam = __expf(Ls[15][tid]);
        blob[OLAM + tid] = lam;
#pragma unroll
        for (int j4 = 0; j4 < 4; j4++) {
            float4 v;
            v.x = Ks[j4 * 4 + 0][tid] * lam; v.y = Ks[j4 * 4 + 1][tid] * lam;
            v.z = Ks[j4 * 4 + 2][tid] * lam; v.w = Ks[j4 * 4 + 3][tid] * lam;
            *(float4*)(blob + OC + tid * 20 + j4 * 4) = v;
        }
        blob[OC + tid * 20 + 16] = lam;
        blob[OC + tid * 20 + 17] = 0.f;
        blob[OC + tid * 20 + 18] = 0.f; blob[OC + tid * 20 + 19] = 0.f;
    }
    {
        const int i = tid >> 4, j = tid & 15;
        float m = 0.f, p = 0.f;
#pragma unroll
        for (int d4 = 0; d4 < 48; d4++) {
            float4 w  = *(const float4*)&Ws[i][d4 * 4];
            float4 ka = *(const float4*)&Ks[j][d4 * 4];
            float4 qa = *(const float4*)&Qs[i][d4 * 4];
            m += w.x * ka.x + w.y * ka.y + w.z * ka.z + w.w * ka.w;
            p += qa.x * ka.x + qa.y * ka.y + qa.z * ka.z + qa.w * ka.w;
        }
        Ms[i][j] = (j < i) ? m : 0.f;
        blob[OPL + tid] = (j <= i) ? p : 0.f;
    }
    __syncthreads();

    float y[16], uu[16];
    const bool doY = (tid < 192);
    const bool doU = (tid >= 128);
    const int dcol = tid, ccol = tid - 128;
    if (doY) {
#pragma unroll
        for (int i = 0; i < 16; i++) y[i] = Ws[i][dcol];
#pragma unroll
        for (int i = 1; i < 16; i++)
#pragma unroll
            for (int j = 0; j < i; j++)
                y[i] = fmaf(-Ms[i][j], y[j], y[i]);
    }
    if (doU) {
#pragma unroll
        for (int i = 0; i < 16; i++)
            uu[i] = bs[i] * kvb[(size_t)(n * 16 + i) * HKV + h * (DNOPE + DV) + DNOPE + ccol];
#pragma unroll
        for (int i = 1; i < 16; i++)
#pragma unroll
            for (int j = 0; j < i; j++)
                uu[i] = fmaf(-Ms[i][j], uu[j], uu[i]);
    }
    if (doY) {
#pragma unroll
        for (int i = 0; i < 16; i++) Xs[i][dcol] = y[i];
    }
    __syncthreads();
#pragma unroll
    for (int s = 0; s < 3; s++) {
        int off = (tid * 3 + s) * 4;
        int r = off / 192, c = off - r * 192;
        *(float4*)(blob + OY + off) = *(const float4*)&Xs[r][c];
    }
    __syncthreads();
    if (doU) {
#pragma unroll
        for (int i = 0; i < 16; i++) Xs[i][ccol] = uu[i];
    }
    __syncthreads();
#pragma unroll
    for (int s = 0; s < 2; s++) {
        int off = (tid * 2 + s) * 4;
        int r = off / 128, c = off - r * 128;
        *(float4*)(blob + OU + off) = *(const float4*)&Xs[r][c];
    }
}

// ---------------------------------------------------------------------------
// Phase B (R14 structure restored — best measured at 105.6 µs — plus one
// change: XCD-aware head swizzle h = bx & 7 so all 64 blocks of a head land
// on one XCD and its L2 holds that head's 3.2 MB pa stream; R15's
// global-register Cb experiment reverted: the compiler sinks "early" global
// loads to use sites (VGPR=64 proved it), exposing L2 latency).
// 512 blocks, triple-buffered LDS staging via global_load_lds, 2 blocks/CU.
// ---------------------------------------------------------------------------
__global__ __launch_bounds__(256) void kda_chunk(
    const float* __restrict__ pa, unsigned short* __restrict__ obh,
    unsigned short* __restrict__ obl)
{
    __shared__ float Cb[3][3840];
    __shared__ float Pb[3][256];
    __shared__ float ubs[3][32];    // u' slice [16 ti][2 cc]
    __shared__ float lbs[3][192];
    __shared__ float Ss[392];       // state [2 cc][196]
    __shared__ float us[40];        // u [2 cc][20]

    const int tid = threadIdx.x;
    const int w = tid >> 6, lane = tid & 63;
    const int h = blockIdx.x & 7, cg = blockIdx.x >> 3;   // XCD swizzle
    const int c0 = cg * 2;

    const int dg  = tid & 15;
    const int cc  = (tid >> 4) & 1;
    const int tig = tid >> 5;
    const int dbase = dg * 12;

    auto stage = [&](int buf, int n) {
        const float* blob = pa + (size_t)(n * 8 + h) * PABLK;
        if (w == 0) {
#pragma unroll
            for (int s = 0; s < 8; s++)
                gl_lds16(blob + OC + s * 256 + lane * 4, &Cb[buf][s * 256]);
        } else if (w == 1) {
#pragma unroll
            for (int s = 8; s < 15; s++)
                gl_lds16(blob + OC + s * 256 + lane * 4, &Cb[buf][s * 256]);
        } else if (w == 2) {
            gl_lds16(blob + OPL + lane * 4, &Pb[buf][0]);
            if (lane < 32)
                gl_lds4(blob + OU + (lane >> 1) * 128 + c0 + (lane & 1), &ubs[buf][0]);
            if (lane < 48)
                gl_lds16(blob + OLAM + lane * 4, &lbs[buf][0]);
        }
    };

    auto ldYQ = [&](int n, float4 (&Y)[2][3], float4 (&Q)[2][3]) {
        const float* blob = pa + (size_t)(n * 8 + h) * PABLK;
#pragma unroll
        for (int i = 0; i < 2; i++) {
            const float* py = blob + OY + (tig * 2 + i) * 192 + dbase;
            const float* pq = blob + OQ + (tig * 2 + i) * 192 + dbase;
#pragma unroll
            for (int s = 0; s < 3; s++) {
                Y[i][s] = *(const float4*)(py + s * 4);
                Q[i][s] = *(const float4*)(pq + s * 4);
            }
        }
    };

    for (int idx = tid; idx < 392; idx += 256) Ss[idx] = 0.f;
    stage(0, 0);
    stage(1, 1);

    float4 YA[2][3], QA[2][3], YB[2][3], QB[2][3];
    ldYQ(0, YA, QA);

    const int c2 = tid & 1, dseg = tid >> 1;   // update map (tid<128 active)

    auto body = [&](int n, int bf, float4 (&Yc)[2][3], float4 (&Qc)[2][3],
                    float4 (&Yn)[2][3], float4 (&Qn)[2][3]) {
        __syncthreads();   // barrier A: bf's tile resident, Ss update visible

        if (n + 2 < TT / 16) {
            int b2 = bf + 2; if (b2 >= 3) b2 -= 3;
            stage(b2, n + 2);
        }
        {
            int np = n + 1; if (np > TT / 16 - 1) np = TT / 16 - 1;
            ldYQ(np, Yn, Qn);
        }

        // z/zq from registers (Y/Q) x LDS (S): 2 ti x 1 cc per thread
        float4 sv[3];
#pragma unroll
        for (int s = 0; s < 3; s++)
            sv[s] = *(const float4*)&Ss[cc * 196 + dbase + s * 4];

        float py[2] = {0.f, 0.f};
        float pq[2] = {0.f, 0.f};
#pragma unroll
        for (int i = 0; i < 2; i++)
#pragma unroll
            for (int s = 0; s < 3; s++) {
                float4 yv = Yc[i][s];
                float4 qv = Qc[i][s];
                float4 s4 = sv[s];
                py[i] = fmaf(yv.x, s4.x, py[i]);
                py[i] = fmaf(yv.y, s4.y, py[i]);
                py[i] = fmaf(yv.z, s4.z, py[i]);
                py[i] = fmaf(yv.w, s4.w, py[i]);
                pq[i] = fmaf(qv.x, s4.x, pq[i]);
                pq[i] = fmaf(qv.y, s4.y, pq[i]);
                pq[i] = fmaf(qv.z, s4.z, pq[i]);
                pq[i] = fmaf(qv.w, s4.w, pq[i]);
            }
        float zy[2], zq[2];
#pragma unroll
        for (int i = 0; i < 2; i++) {
            zy[i] = red16(py[i]);
            zq[i] = red16(pq[i]);
        }

        float uv[2];
#pragma unroll
        for (int i = 0; i < 2; i++)
            uv[i] = ubs[bf][(tig * 2 + i) * 2 + cc] - zy[i];
        if ((dg & 7) == 0) {
            const int ii = dg >> 3;
            us[cc * 20 + tig * 2 + ii] = (ii == 0) ? uv[0] : uv[1];
        }
        __syncthreads();   // barrier B: us ready

        {
            const int ii = dg >> 3, qtr = dg & 7;
            const int ti = tig * 2 + ii;
            float acc = 0.f;
#pragma unroll
            for (int j = qtr; j <= 15; j += 8)
                if (j <= ti) acc = fmaf(Pb[bf][ti * 16 + j], us[cc * 20 + j], acc);
            acc = red8(acc);
            if (qtr == 0) {
                float ov = zq[ii] + acc;
                if (isnan(ov)) ov = 0.f;
                else if (isinf(ov)) ov = ov > 0.f ? 1e4f : -1e4f;
                size_t oi = (size_t)(n * 16 + ti) * (HH * DV) + h * DV + c0 + cc;
                unsigned short hb = f2bf_rn(ov);
                obh[oi] = hb;
                obl[oi] = f2bf_rn(ov - bf2f(hb));
            }
        }

        if (tid < 128) {
            const float4* up = (const float4*)&us[c2 * 20];
            float4 u0 = up[0], u1 = up[1], u2v = up[2], u3 = up[3];
#pragma unroll
            for (int s = 0; s < 3; s++) {
                int d = dseg * 3 + s;
                float svv = Ss[c2 * 196 + d];
                float a2 = lbs[bf][d] * svv;
                const float4* C4 = (const float4*)&Cb[bf][d * 20];
                float4 k0 = C4[0], k1 = C4[1], k2 = C4[2], k3 = C4[3];
                a2 = fmaf(k0.x, u0.x,  a2); a2 = fmaf(k0.y, u0.y,  a2);
                a2 = fmaf(k0.z, u0.z,  a2); a2 = fmaf(k0.w, u0.w,  a2);
                a2 = fmaf(k1.x, u1.x,  a2); a2 = fmaf(k1.y, u1.y,  a2);
                a2 = fmaf(k1.z, u1.z,  a2); a2 = fmaf(k1.w, u1.w,  a2);
                a2 = fmaf(k2.x, u2v.x, a2); a2 = fmaf(k2.y, u2v.y, a2);
                a2 = fmaf(k2.z, u2v.z, a2); a2 = fmaf(k2.w, u2v.w, a2);
                a2 = fmaf(k3.x, u3.x,  a2); a2 = fmaf(k3.y, u3.y,  a2);
                a2 = fmaf(k3.z, u3.z,  a2); a2 = fmaf(k3.w, u3.w,  a2);
                Ss[c2 * 196 + d] = a2;
            }
        }
        // no barrier C: next body's barrier A orders Ss/us reuse
    };

    int buf = 0;
    for (int n = 0; n < TT / 16; n += 2) {
        body(n, buf, YA, QA, YB, QB);
        int b1 = buf + 1; if (b1 >= 3) b1 -= 3;
        body(n + 1, b1, YB, QB, YA, QA);
        buf += 2; if (buf >= 3) buf -= 3;
    }
}

// ---------------------------------------------------------------------------
extern "C" void kernel_launch(void* const* d_in, const int* in_sizes, int n_in,
                              void* d_out, int out_size, void* d_ws, size_t ws_size,
                              hipStream_t stream)
{
    const float* x         = (const float*)d_in[0];
    // d_in[1] = cos, d_in[2] = sin : unused by the reference
    const float* wq_a      = (const float*)d_in[3];
    const float* q_norm_w  = (const float*)d_in[4];
    const float* wq_b      = (const float*)d_in[5];
    const float* wkv_a     = (const float*)d_in[6];
    const float* kv_norm_w = (const float*)d_in[7];
    const float* wkv_b     = (const float*)d_in[8];
    const float* wg_w      = (const float*)d_in[9];
    const float* wg_b      = (const float*)d_in[10];
    const float* wb        = (const float*)d_in[11];
    const float* wo        = (const float*)d_in[12];
    float* out = (float*)d_out;

    float* ws = (float*)d_ws;
    float* xq     = ws;                        // T x 768 (f32, gemm1 out)
    float* kv_all = xq     + TT * QLR;         // T x 576
    float* agraw  = kv_all + TT * (KVLR + DROPE); // T x 1536 (dead after logsig)
    float* qnraw  = agraw  + TT * HDK;         // T x 1536
    float* kvb    = qnraw  + TT * HDK;         // T x 2048
    float* la_h   = kvb    + TT * HKV;         // 8 x 1024 x 192
    float* q_h    = la_h   + TT * HDK;
    float* k_h    = q_h    + TT * HDK;
    float* betab  = k_h    + TT * HDK;         // T x 8
    float* pa     = betab  + TT * HH;          // 512 x PABLK (25.6 MB)
    float* tail   = pa     + 512 * PABLK;

    unsigned short* wo_h  = (unsigned short*)tail;          // 1024*1024
    unsigned short* wo_l  = wo_h  + 1048576;
    unsigned short* xh    = wo_l  + 1048576;                // 1024*1024
    unsigned short* xl    = xh    + 1048576;
    unsigned short* xqh   = xl    + 1048576;                // 1024*768
    unsigned short* xql   = xqh   + 786432;
    unsigned short* kvnh  = xql   + 786432;                 // 1024*512
    unsigned short* kvnl  = kvnh  + 524288;

    unsigned short* wqa_h  = (unsigned short*)pa;           // 768n x 1024k
    unsigned short* wqa_l  = wqa_h  + 786432;
    unsigned short* wkva_h = wqa_l  + 786432;               // 576n x 1024k
    unsigned short* wkva_l = wkva_h + 589824;
    unsigned short* wgw_h  = wkva_l + 589824;               // 1536n x 1024k
    unsigned short* wgw_l  = wgw_h  + 1572864;
    unsigned short* wqb_h  = wgw_l  + 1572864;              // 1536n x 768k
    unsigned short* wqb_l  = wqb_h  + 1179648;
    unsigned short* wkvb_h = wqb_l  + 1179648;              // 2048n x 512k
    unsigned short* wkvb_l = wkvb_h + 1048576;

    unsigned short* obh = (unsigned short*)agraw;           // 1024*1024
    unsigned short* obl = obh + 1048576;

    dim3 blk(256);

    wconv<<<dim3(192 + 144 + 384), blk, 0, stream>>>(
        wq_a, wqa_h, wqa_l, DIM, QLR, 192,
        wkv_a, wkva_h, wkva_l, DIM, KVLR + DROPE, 144,
        wg_w, wgw_h, wgw_l, DIM, HDK, 384);
    wconv<<<dim3(288 + 256 + 256), blk, 0, stream>>>(
        wq_b, wqb_h, wqb_l, QLR, HDK, 288,
        wkv_b, wkvb_h, wkvb_l, KVLR, HKV, 256,
        wo, wo_h, wo_l, DIM, DIM, 256);

    aconv<<<dim3(TT * DIM / (256 * 8)), blk, 0, stream>>>(x, xh, xl);

    gemm_bt<<<dim3(12 + 9 + 24, 16), dim3(128), 0, stream>>>(
        xh, xl, wqa_h, wqa_l, xq, DIM, QLR, 12,
        xh, xl, wkva_h, wkva_l, kv_all, DIM, KVLR + DROPE, 9,
        xh, xl, wgw_h, wgw_l, agraw, DIM, HDK, 24);

    rmsnorm_bf2<<<dim3(2 * TT), blk, 0, stream>>>(
        xq, q_norm_w, xqh, xql,
        kv_all, kv_norm_w, kvnh, kvnl);

    gemm_bt<<<dim3(24 + 32, 16), dim3(128), 0, stream>>>(
        xqh, xql, wqb_h, wqb_l, qnraw, QLR, HDK, 24,
        kvnh, kvnl, wkvb_h, wkvb_l, kvb, KVLR, HKV, 32,
        xh, xl, wqa_h, wqa_l, xq, DIM, QLR, 0);

    small_fused<<<dim3(6144 + 2048 + 2048), blk, 0, stream>>>(
        agraw, wg_b, la_h,
        x, wb, betab,
        qnraw, kvb, kv_all, q_h, k_h);

    chunk_prep<<<512, blk, 0, stream>>>(k_h, la_h, q_h, kvb, betab, pa);
    kda_chunk<<<512, blk, 0, stream>>>(pa, obh, obl);

    gemm_bt<<<dim3(16, 16), dim3(128), 0, stream>>>(
        obh, obl, wo_h, wo_l, out, DIM, DIM, 16,
        xh, xl, wqa_h, wqa_l, xq, DIM, QLR, 0,
        xh, xl, wqa_h, wqa_l, xq, DIM, QLR, 0);
}